// Round 3
// baseline (225.415 us; speedup 1.0000x reference)
//
#include <hip/hip_runtime.h>

#define KK 49
#define BLK 256
#define PPW 32                 // pixels per wave (TPP=2)
#define PPB 128                // pixels per block (4 waves)
#define WFL (PPW * KK)         // floats per wave slice = 1568
#define WF4 (WFL / 4)          // float4 per wave slice = 392

typedef float v2f __attribute__((ext_vector_type(2)));

static __device__ __forceinline__ v2f v2bc(float s) { v2f r; r.x = s; r.y = s; return r; }

// Catmull-Rom a=-0.5, branchless, packed 2-wide:
// w = 0.5*t2^3 - 0.5*t2^2 + t1^2 - 2*t1^3,  t2=max(0,2-|x|), t1=max(0,1-|x|)
static __device__ __forceinline__ v2f cubic2(v2f x) {
    v2f ax = __builtin_elementwise_abs(x);
    v2f t2 = __builtin_elementwise_max(v2bc(2.0f) - ax, v2bc(0.0f));
    v2f t1 = __builtin_elementwise_max(v2bc(1.0f) - ax, v2bc(0.0f));
    v2f r  = (t2 * t2) * __builtin_elementwise_fma(v2bc(0.5f), t2, v2bc(-0.5f));
    return __builtin_elementwise_fma(t1 * t1,
              __builtin_elementwise_fma(v2bc(-2.0f), t1, v2bc(1.0f)), r);
}

__global__ __launch_bounds__(BLK, 4) void kest_kernel(
    const float* __restrict__ m,
    const float* __restrict__ grid,
    const int*   __restrict__ Wp,
    const int*   __restrict__ yi,
    float*       __restrict__ out,
    int N)
{
    __shared__ __align__(16) float lds[4 * WFL];   // 25088 B -> 6 blocks/CU (LDS-capped)

    const int tid   = threadIdx.x;
    const int wv_   = tid >> 6;          // wave id 0..3
    const int lane  = tid & 63;
    const int pixW  = lane >> 1;         // pixel-in-wave 0..31
    const int sub   = lane & 1;          // which half of the 49 weights
    const int blockBase = blockIdx.x * PPB;
    float* ldsW = &lds[wv_ * WFL];       // wave-private slice: NO barrier needed

    // ---- setup: lanes 0..31 each compute coeffs for pixel (waveBase+lane) ----
    float Axx = 0.f, Axy = 0.f, Ayx = 0.f, Ayy = 0.f, fxc = 0.f, fyc = 0.f;
    if (lane < 32) {
        const int p = blockBase + wv_ * PPW + lane;
        if (p < N) {
            const float m00 = m[0], m01 = m[1], m02 = m[2];
            const float m10 = m[3], m11 = m[4], m12 = m[5];
            const float m20 = m[6], m21 = m[7], m22 = m[8];
            const int   W   = Wp[0];

            const int j = yi[p];
            int yyI, xxI;
            if ((W & (W - 1)) == 0) {            // uniform branch (W=1024)
                yyI = j >> (__ffs(W) - 1);
                xxI = j & (W - 1);
            } else {
                yyI = j / W;
                xxI = j - yyI * W;
            }
            const float xx = (float)xxI, yy = (float)yyI;

            const float X0 = m00 * xx + m01 * yy + m02;
            const float Y0 = m10 * xx + m11 * yy + m12;
            const float Z0 = m20 * xx + m21 * yy + m22;

            // stable difference-of-quotients: du (eps_y=±0.5), dv (eps_x=±0.5)
            const float izy = __builtin_amdgcn_rcpf(Z0 * Z0 - 0.25f * m21 * m21);
            float du0 = (m01 * Z0 - m21 * X0) * izy;
            float du1 = (m11 * Z0 - m21 * Y0) * izy;
            const float izx = __builtin_amdgcn_rcpf(Z0 * Z0 - 0.25f * m20 * m20);
            float dv0 = (m00 * Z0 - m20 * X0) * izx;
            float dv1 = (m10 * Z0 - m20 * Y0) * izx;

            const float d2u = du0 * du0 + du1 * du1;
            const float rlu = __builtin_amdgcn_rsqf(d2u);
            float len_du = d2u * rlu;
            if (len_du < 1.0f) { du0 *= rlu; du1 *= rlu; len_du = 1.0f; }
            const float d2v = dv0 * dv0 + dv1 * dv1;
            const float rlv = __builtin_amdgcn_rsqf(d2v);
            float len_dv = d2v * rlv;
            if (len_dv < 1.0f) { dv0 *= rlv; dv1 *= rlv; len_dv = 1.0f; }

            const float det  = du0 * dv1 - du1 * dv0;
            const float r_du = __builtin_amdgcn_rcpf(len_du * det);
            const float r_dv = __builtin_amdgcn_rcpf(len_dv * det);

            const float p1 = du0 * dv1, p2 = du1 * dv0;
            Axx = p1 * r_du - p2 * r_dv;
            Axy = du0 * du1 * (r_dv - r_du);
            Ayx = dv0 * dv1 * (r_du - r_dv);
            Ayy = p1 * r_dv - p2 * r_du;

            const float px = grid[p]     + 0.5f;
            const float py = grid[N + p] + 0.5f;
            fxc = (px - __builtin_floorf(px)) + 2.5f;
            fyc = (py - __builtin_floorf(py)) + 2.5f;
        }
    }
    // distribute coeffs: lane needs values from setup-lane pixW (0..31)
    Axx = __shfl(Axx, pixW); Axy = __shfl(Axy, pixW);
    Ayx = __shfl(Ayx, pixW); Ayy = __shfl(Ayy, pixW);
    fxc = __shfl(fxc, pixW); fyc = __shfl(fyc, pixW);

    const int i = blockBase + wv_ * PPW + pixW;   // this lane's pixel
    float rs = 0.0f;                              // 1/wsum, needed in drain
    if (i < N) {
        const float subf = (float)sub;
        const v2f subf2 = v2bc(subf);
        const v2f Axx2 = v2bc(Axx), Axy2 = v2bc(Axy);
        const v2f Ayx2 = v2bc(Ayx), Ayy2 = v2bc(Ayy);

        // LDS write addr = pixW*49 + 4j + 2e + sub; banks 17*pixW+sub mod 32
        // -> at most 2-way aliasing (free).  Weights stored UNNORMALIZED;
        // normalization happens in the drain (frees the 13-entry reg array).
        float* base = &ldsW[pixW * KK + sub];

        // weights q = 4j + 2e + sub  (e = vector half), j = 0..12
        v2f ws2 = v2bc(0.0f);
#pragma unroll
        for (int j = 0; j < 13; ++j) {
            const int q0 = 4 * j, q1 = 4 * j + 2;
            const float cx0 = (float)(q0 % 7), cx1 = (float)(q1 % 7);
            const float dx0 = (float)((q0 + 1) % 7 - q0 % 7);
            const float dx1 = (float)((q1 + 1) % 7 - q1 % 7);
            const float ry0 = (float)(q0 / 7), ry1 = (float)(q1 / 7);
            const float dy0 = (float)((q0 + 1) / 7 - q0 / 7);
            const float dy1 = (float)((q1 + 1) / 7 - q1 / 7);

            v2f wxv; wxv.x = fxc - cx0; wxv.y = fxc - cx1;
            v2f dxv; dxv.x = -dx0;      dxv.y = -dx1;
            wxv = __builtin_elementwise_fma(subf2, dxv, wxv);
            v2f wyv; wyv.x = fyc - ry0; wyv.y = fyc - ry1;
            v2f dyv; dyv.x = -dy0;      dyv.y = -dy1;
            wyv = __builtin_elementwise_fma(subf2, dyv, wyv);

            v2f x2 = __builtin_elementwise_fma(Axx2, wxv, Axy2 * wyv);
            v2f y2 = __builtin_elementwise_fma(Ayx2, wxv, Ayy2 * wyv);
            v2f w2 = cubic2(x2) * cubic2(y2);
            if (j == 12) {                 // q = 48+sub / 50+sub: mask invalid
                w2.x *= (1.0f - subf);
                w2.y  = 0.0f;
            }
            ws2 += w2;
            if (j < 12) {
                base[4 * j]     = w2.x;
                base[4 * j + 2] = w2.y;
            } else if (sub == 0) {
                base[48] = w2.x;           // q=48 only; q>=49 would corrupt
            }
        }
        float wsum = ws2.x + ws2.y;
        wsum += __shfl_xor(wsum, 1);       // combine the pixel's two lanes
        rs = __builtin_amdgcn_rcpf(wsum);
    }

    // ---- wave-private drain, no barrier: compiler's lgkmcnt wait suffices ----
    // normalize on the fly: float f belongs to pixel f/49; its rs lives in
    // lane 2*(f/49).  f/49 == (f*669)>>15 exactly for f <= 1567.
    // CONVERGENCE: every __shfl (ds_bpermute) must execute with ALL lanes
    // active — a bpermute read from an exec-masked-off lane returns 0.
    // So shuffles use a CLAMPED index outside the guards; only the LDS load
    // and global store sit under divergent control flow.
    const long long dstF4 = (long long)blockIdx.x * (PPB * KK / 4) + wv_ * WF4;
    if (blockBase + PPB <= N) {            // uniform fast path: block fully valid
        const float4* src = (const float4*)ldsW;
        float4* dst = (float4*)out + dstF4;
#pragma unroll
        for (int k = 0; k < 7; ++k) {
            const int t = lane + 64 * k;
            const bool valid = (t < WF4);  // k<6: uniformly true; k=6: lanes 0..7
            const int tc = valid ? t : 0;  // clamped addr for convergent shfl
            const int f0 = 4 * tc;
            // a float4 spans at most one 49-boundary: 2 shuffles + selects
            const int pA = (f0 * 669) >> 15;
            const int pB = ((f0 + 3) * 669) >> 15;
            const float rA = __shfl(rs, pA << 1);   // convergent: all lanes
            const float rB = __shfl(rs, pB << 1);
            const int bnd = 49 * pA + 49 - f0;      // components >= bnd use rB
            if (valid) {
                float4 v = src[t];
                v.x *= rA;                          // component 0 < bnd always
                v.y *= (1 < bnd) ? rA : rB;
                v.z *= (2 < bnd) ? rA : rB;
                v.w *= (3 < bnd) ? rA : rB;
                dst[t] = v;
            }
        }
    } else {                               // tail block: scalar, bounds-checked
        const float* s = (const float*)ldsW;
        const long long baseF = dstF4 * 4;
        const long long limF  = (long long)N * KK;
#pragma unroll 1
        for (int k = 0; k < (WFL + 63) / 64; ++k) {   // fixed 25 trips: uniform
            const int t = lane + 64 * k;
            const int tc = (t < WFL) ? t : 0;
            const float r = __shfl(rs, ((tc * 669) >> 15) << 1);  // convergent
            if (t < WFL && baseF + t < limF)
                out[baseF + t] = s[t] * r;
        }
    }
}

extern "C" void kernel_launch(void* const* d_in, const int* in_sizes, int n_in,
                              void* d_out, int out_size, void* d_ws, size_t ws_size,
                              hipStream_t stream) {
    // inputs: m_inverse(9 f32), grid(2N f32), H(1 i32), W(1 i32), yi(N i32)
    const float* m    = (const float*)d_in[0];
    const float* grid = (const float*)d_in[1];
    const int*   Wp   = (const int*)d_in[3];
    const int*   yi   = (const int*)d_in[4];
    float*       out  = (float*)d_out;
    const int N = in_sizes[4];

    const int blocks = (N + PPB - 1) / PPB;
    kest_kernel<<<blocks, BLK, 0, stream>>>(m, grid, Wp, yi, out, N);
}